// Round 3
// baseline (316.428 us; speedup 1.0000x reference)
//
#include <hip/hip_runtime.h>

#define L_DIM 1024
#define B_DIM 16
#define D_DIM 1024
#define K_DIM 1024            // = D
#define N_DIM 3072            // = 3*D
#define M_DIM (L_DIM * B_DIM) // 16384
#define CHAINS 16384          // B*D
#define CHUNK 32              // steps per chunk
#define NCHUNK 32             // L / CHUNK

typedef float f32x4 __attribute__((ext_vector_type(4)));
typedef __bf16 bf16x8 __attribute__((ext_vector_type(8)));
typedef unsigned short u16;
typedef unsigned int u32;
typedef u16 u16x8 __attribute__((ext_vector_type(8)));

__device__ __forceinline__ u16 f2bf(float f) {
  u32 u = __float_as_uint(f);
  u = u + 0x7FFFu + ((u >> 16) & 1u);   // round-to-nearest-even
  return (u16)(u >> 16);
}
__device__ __forceinline__ float bf2f(u16 v) {
  return __uint_as_float(((u32)v) << 16);
}
__device__ __forceinline__ float fexp(float v) {
  return __builtin_amdgcn_exp2f(v * 1.4426950408889634f);
}
__device__ __forceinline__ float sigm(float z) {
  return __builtin_amdgcn_rcpf(1.0f + fexp(-z));
}
__device__ __forceinline__ float ftanh(float v) {
  return 1.0f - 2.0f * __builtin_amdgcn_rcpf(1.0f + fexp(2.0f * v));
}

// ---------------- x: fp32 -> bf16 straight cast ----------------
__global__ __launch_bounds__(256) void cvt_x_kernel(const float4* __restrict__ in,
                                                    ushort4* __restrict__ out, int n4) {
  int i = blockIdx.x * 256 + threadIdx.x;
  if (i < n4) {
    float4 v = in[i];
    ushort4 o;
    o.x = f2bf(v.x); o.y = f2bf(v.y); o.z = f2bf(v.z); o.w = f2bf(v.w);
    out[i] = o;
  }
}

// ---------------- W (K x N fp32) -> Wt (N' x K bf16), plane-major N permute ----------------
__global__ __launch_bounds__(256) void cvt_w_kernel(const float* __restrict__ W,
                                                    u16* __restrict__ Wt) {
  __shared__ float tile[64][65];
  int c0 = blockIdx.x * 64;  // N block
  int r0 = blockIdx.y * 64;  // K block
  int tx = threadIdx.x & 63;
  int ty = threadIdx.x >> 6;
#pragma unroll
  for (int i = 0; i < 16; ++i) {
    int row = i * 4 + ty;
    tile[row][tx] = W[(size_t)(r0 + row) * N_DIM + c0 + tx];
  }
  __syncthreads();
#pragma unroll
  for (int i = 0; i < 16; ++i) {
    int crow = i * 4 + ty;
    int c = c0 + crow;
    int nprime = (c % 3) * D_DIM + (c / 3);
    Wt[(size_t)nprime * K_DIM + r0 + tx] = f2bf(tile[tx][crow]);
  }
}

// ---------------- GEMM: U(M x N bf16) = A(M x K bf16) @ Wt^T, m97 structure ----------------
__global__ __launch_bounds__(256) void gemm_kernel(const u16* __restrict__ A,
                                                   const u16* __restrict__ Bt,
                                                   u16* __restrict__ U) {
  __shared__ __align__(16) char smem[128 * 132 * 2];  // 33792 B; K-loop uses first 16 KB
  u16* lA = (u16*)smem;
  u16* lB = (u16*)(smem + 8192);
  const int tid = threadIdx.x;
  const int wave = tid >> 6;
  const int lane = tid & 63;
  const int wm = wave >> 1, wn = wave & 1;
  const int quad = lane >> 4, l16 = lane & 15;
  const int m0 = blockIdx.y * 128;
  const int n0 = blockIdx.x * 128;

  f32x4 acc[4][4] = {};

  const u16* gA = A + (size_t)(m0 + (tid >> 2)) * K_DIM + (tid & 3) * 8;
  const u16* gB = Bt + (size_t)(n0 + (tid >> 2)) * K_DIM + (tid & 3) * 8;
  u16* sA0 = lA + wave * 512;
  u16* sA1 = lA + 2048 + wave * 512;
  u16* sB0 = lB + wave * 512;
  u16* sB1 = lB + 2048 + wave * 512;

  const u16* rA = lA + (wm * 64 + l16) * 32 + quad * 8;
  const u16* rB = lB + (wn * 64 + l16) * 32 + quad * 8;

  for (int k0 = 0; k0 < K_DIM; k0 += 32) {
    __syncthreads();
    __builtin_amdgcn_global_load_lds((const __attribute__((address_space(1))) void*)(gA + k0),
                                     (__attribute__((address_space(3))) void*)sA0, 16, 0, 0);
    __builtin_amdgcn_global_load_lds((const __attribute__((address_space(1))) void*)(gA + (size_t)64 * K_DIM + k0),
                                     (__attribute__((address_space(3))) void*)sA1, 16, 0, 0);
    __builtin_amdgcn_global_load_lds((const __attribute__((address_space(1))) void*)(gB + k0),
                                     (__attribute__((address_space(3))) void*)sB0, 16, 0, 0);
    __builtin_amdgcn_global_load_lds((const __attribute__((address_space(1))) void*)(gB + (size_t)64 * K_DIM + k0),
                                     (__attribute__((address_space(3))) void*)sB1, 16, 0, 0);
    __syncthreads();

    bf16x8 af[4], bfr[4];
#pragma unroll
    for (int mt = 0; mt < 4; ++mt) af[mt] = *(const bf16x8*)(rA + mt * 16 * 32);
#pragma unroll
    for (int nt = 0; nt < 4; ++nt) bfr[nt] = *(const bf16x8*)(rB + nt * 16 * 32);
#pragma unroll
    for (int mt = 0; mt < 4; ++mt)
#pragma unroll
      for (int nt = 0; nt < 4; ++nt)
        acc[mt][nt] = __builtin_amdgcn_mfma_f32_16x16x32_bf16(af[mt], bfr[nt], acc[mt][nt], 0, 0, 0);
  }

  // ---- epilogue: acc -> LDS (bf16, stride 132: 2-way-free writes) -> dwordx4 stores ----
  __syncthreads();  // all waves done reading lA/lB before overwrite
  u16* lC = (u16*)smem;
#pragma unroll
  for (int mt = 0; mt < 4; ++mt) {
#pragma unroll
    for (int nt = 0; nt < 4; ++nt) {
      int row = wm * 64 + mt * 16 + quad * 4;
      int col = wn * 64 + nt * 16 + l16;
#pragma unroll
      for (int r = 0; r < 4; ++r)
        lC[(row + r) * 132 + col] = f2bf(acc[mt][nt][r]);
    }
  }
  __syncthreads();
  int g = tid & 15;        // col group (8 u16 each)
  int r0w = tid >> 4;      // 16 rows per iteration
#pragma unroll
  for (int it = 0; it < 8; ++it) {
    int row = r0w + it * 16;
    const u16* src = lC + row * 132 + g * 8;
    uint2 lo = *(const uint2*)src;          // 8B-aligned (row*264 % 8 == 0)
    uint2 hi = *(const uint2*)(src + 4);
    uint4 v = make_uint4(lo.x, lo.y, hi.x, hi.y);
    *(uint4*)(U + (size_t)(m0 + row) * N_DIM + n0 + g * 8) = v;
  }
}

// ---------------- SRU chunked affine scan, 8 chains per lane ----------------
// U plane-major: U[m*3072 + k*1024 + d]; lane owns d0..d0+7 (one b), so all plane
// reads are bf16x8 (16B/lane) and x/h are 2x float4.

__global__ __launch_bounds__(256) void sru_phase1(const u16* __restrict__ U,
                                                  const float* __restrict__ bias,
                                                  float* __restrict__ Aarr,
                                                  float* __restrict__ Barr) {
  int tid = blockIdx.x * 256 + threadIdx.x;   // [NCHUNK][B][128]
  int j = tid >> 11;
  int b = (tid >> 7) & 15;
  int dg = tid & 127;
  int d0 = dg * 8;
  int chain0 = b * D_DIM + d0;
  float bb1[8];
#pragma unroll
  for (int i = 0; i < 8; ++i) bb1[i] = bias[d0 + i];
  const u16* p = U + (size_t)(j * CHUNK * B_DIM + b) * N_DIM + d0;
  float A[8], Bv[8];
#pragma unroll
  for (int i = 0; i < 8; ++i) { A[i] = 1.0f; Bv[i] = 0.0f; }
#pragma unroll 4
  for (int s = 0; s < CHUNK; ++s) {
    u16x8 u0v = *(const u16x8*)p;
    u16x8 g1v = *(const u16x8*)(p + D_DIM);
#pragma unroll
    for (int i = 0; i < 8; ++i) {
      float u0 = bf2f(u0v[i]);
      float g1 = sigm(bf2f(g1v[i]) + bb1[i]);
      Bv[i] = (Bv[i] - u0) * g1 + u0;
      A[i] *= g1;
    }
    p += (size_t)B_DIM * N_DIM;
  }
  float* Ap = Aarr + (size_t)j * CHAINS + chain0;
  float* Bp = Barr + (size_t)j * CHAINS + chain0;
  *(float4*)Ap = make_float4(A[0], A[1], A[2], A[3]);
  *(float4*)(Ap + 4) = make_float4(A[4], A[5], A[6], A[7]);
  *(float4*)Bp = make_float4(Bv[0], Bv[1], Bv[2], Bv[3]);
  *(float4*)(Bp + 4) = make_float4(Bv[4], Bv[5], Bv[6], Bv[7]);
}

__global__ __launch_bounds__(256) void sru_phase2(const float* __restrict__ Aarr,
                                                  const float* __restrict__ Barr,
                                                  const float* __restrict__ c0,
                                                  float* __restrict__ Cin,
                                                  float* __restrict__ clast) {
  int chain = blockIdx.x * 256 + threadIdx.x;
  float c = c0[chain];
#pragma unroll
  for (int j = 0; j < NCHUNK; ++j) {
    Cin[j * CHAINS + chain] = c;
    c = Aarr[j * CHAINS + chain] * c + Barr[j * CHAINS + chain];
  }
  clast[chain] = c;
}

__global__ __launch_bounds__(256) void sru_phase3(const u16* __restrict__ U,
                                                  const float* __restrict__ x,
                                                  const float* __restrict__ bias,
                                                  const float* __restrict__ Cin,
                                                  float* __restrict__ h) {
  int tid = blockIdx.x * 256 + threadIdx.x;
  int j = tid >> 11;
  int b = (tid >> 7) & 15;
  int dg = tid & 127;
  int d0 = dg * 8;
  int chain0 = b * D_DIM + d0;
  float bb1[8], bb2[8], c[8];
#pragma unroll
  for (int i = 0; i < 8; ++i) {
    bb1[i] = bias[d0 + i];
    bb2[i] = bias[D_DIM + d0 + i];
  }
  const float* cin = Cin + (size_t)j * CHAINS + chain0;
#pragma unroll
  for (int i = 0; i < 8; ++i) c[i] = cin[i];
  size_t m0 = (size_t)(j * CHUNK * B_DIM + b);
  const u16* p = U + m0 * N_DIM + d0;
  const float* xp = x + m0 * D_DIM + d0;
  float* hp = h + m0 * D_DIM + d0;
#pragma unroll 2
  for (int s = 0; s < CHUNK; ++s) {
    u16x8 u0v = *(const u16x8*)p;
    u16x8 g1v = *(const u16x8*)(p + D_DIM);
    u16x8 g2v = *(const u16x8*)(p + 2 * D_DIM);
    float4 x0 = *(const float4*)xp;
    float4 x1 = *(const float4*)(xp + 4);
    float xs[8] = {x0.x, x0.y, x0.z, x0.w, x1.x, x1.y, x1.z, x1.w};
    float hs[8];
#pragma unroll
    for (int i = 0; i < 8; ++i) {
      float u0 = bf2f(u0v[i]);
      float g1 = sigm(bf2f(g1v[i]) + bb1[i]);
      float g2 = sigm(bf2f(g2v[i]) + bb2[i]);
      c[i] = (c[i] - u0) * g1 + u0;
      hs[i] = (ftanh(c[i]) - xs[i]) * g2 + xs[i];
    }
    *(float4*)hp = make_float4(hs[0], hs[1], hs[2], hs[3]);
    *(float4*)(hp + 4) = make_float4(hs[4], hs[5], hs[6], hs[7]);
    p += (size_t)B_DIM * N_DIM;
    xp += B_DIM * D_DIM;
    hp += B_DIM * D_DIM;
  }
}

extern "C" void kernel_launch(void* const* d_in, const int* in_sizes, int n_in,
                              void* d_out, int out_size, void* d_ws, size_t ws_size,
                              hipStream_t stream) {
  const float* x = (const float*)d_in[0];     // L*B*D
  const float* W = (const float*)d_in[1];     // K x 3D
  const float* bias = (const float*)d_in[2];  // 2D
  const float* c0 = (const float*)d_in[3];    // B*D
  float* out = (float*)d_out;

  char* ws = (char*)d_ws;
  u16* xb = (u16*)ws;                               // 32 MiB, dead after gemm
  u16* wt = (u16*)(ws + 33554432);                  // 6 MiB
  u16* U = (u16*)(ws + 33554432 + 6291456);         // 96 MiB
  // scan scratch overlaps dead xb region (gemm consumed xb before phase1 runs)
  float* Aarr = (float*)ws;                         // 2 MiB
  float* Barr = (float*)(ws + 2097152);             // 2 MiB
  float* Cin  = (float*)(ws + 4194304);             // 2 MiB

  cvt_x_kernel<<<16384, 256, 0, stream>>>((const float4*)x, (ushort4*)xb, M_DIM * K_DIM / 4);
  cvt_w_kernel<<<dim3(48, 16), 256, 0, stream>>>(W, wt);
  gemm_kernel<<<dim3(N_DIM / 128, M_DIM / 128), 256, 0, stream>>>(xb, wt, U);
  sru_phase1<<<CHAINS * NCHUNK / 8 / 256, 256, 0, stream>>>(U, bias, Aarr, Barr);
  sru_phase2<<<CHAINS / 256, 256, 0, stream>>>(Aarr, Barr, c0, Cin, out + (size_t)M_DIM * D_DIM);
  sru_phase3<<<CHAINS * NCHUNK / 8 / 256, 256, 0, stream>>>(U, x, bias, Cin, out);
}

// Round 4
// 302.400 us; speedup vs baseline: 1.0464x; 1.0464x over previous
//
#include <hip/hip_runtime.h>

#define L_DIM 1024
#define B_DIM 16
#define D_DIM 1024
#define K_DIM 1024            // = D
#define N_DIM 3072            // = 3*D
#define M_DIM (L_DIM * B_DIM) // 16384
#define CHAINS 16384          // B*D
#define CHUNK 16              // steps per chunk
#define NCHUNK 64             // L / CHUNK

typedef float f32x4 __attribute__((ext_vector_type(4)));
typedef __bf16 bf16x8 __attribute__((ext_vector_type(8)));
typedef unsigned short u16;
typedef unsigned int u32;
typedef u16 u16x8 __attribute__((ext_vector_type(8)));

__device__ __forceinline__ u16 f2bf(float f) {
  u32 u = __float_as_uint(f);
  u = u + 0x7FFFu + ((u >> 16) & 1u);   // round-to-nearest-even
  return (u16)(u >> 16);
}
__device__ __forceinline__ float bf2f(u16 v) {
  return __uint_as_float(((u32)v) << 16);
}
__device__ __forceinline__ float fexp(float v) {
  return __builtin_amdgcn_exp2f(v * 1.4426950408889634f);
}
__device__ __forceinline__ float sigm(float z) {
  return __builtin_amdgcn_rcpf(1.0f + fexp(-z));
}
__device__ __forceinline__ float ftanh(float v) {
  return 1.0f - 2.0f * __builtin_amdgcn_rcpf(1.0f + fexp(2.0f * v));
}

// ---------------- x: fp32 -> bf16 straight cast ----------------
__global__ __launch_bounds__(256) void cvt_x_kernel(const float4* __restrict__ in,
                                                    ushort4* __restrict__ out, int n4) {
  int i = blockIdx.x * 256 + threadIdx.x;
  if (i < n4) {
    float4 v = in[i];
    ushort4 o;
    o.x = f2bf(v.x); o.y = f2bf(v.y); o.z = f2bf(v.z); o.w = f2bf(v.w);
    out[i] = o;
  }
}

// ---------------- W (K x N fp32) -> Wt (N' x K bf16), plane-major N permute ----------------
__global__ __launch_bounds__(256) void cvt_w_kernel(const float* __restrict__ W,
                                                    u16* __restrict__ Wt) {
  __shared__ float tile[64][65];
  int c0 = blockIdx.x * 64;  // N block
  int r0 = blockIdx.y * 64;  // K block
  int tx = threadIdx.x & 63;
  int ty = threadIdx.x >> 6;
#pragma unroll
  for (int i = 0; i < 16; ++i) {
    int row = i * 4 + ty;
    tile[row][tx] = W[(size_t)(r0 + row) * N_DIM + c0 + tx];
  }
  __syncthreads();
#pragma unroll
  for (int i = 0; i < 16; ++i) {
    int crow = i * 4 + ty;
    int c = c0 + crow;
    int nprime = (c % 3) * D_DIM + (c / 3);
    Wt[(size_t)nprime * K_DIM + r0 + tx] = f2bf(tile[tx][crow]);
  }
}

// ---------------- GEMM: U(M x N bf16) = A(M x K bf16) @ Wt^T, m97 structure ----------------
__global__ __launch_bounds__(256) void gemm_kernel(const u16* __restrict__ A,
                                                   const u16* __restrict__ Bt,
                                                   u16* __restrict__ U) {
  __shared__ __align__(16) char smem[128 * 132 * 2];  // 33792 B; K-loop uses first 16 KB
  u16* lA = (u16*)smem;
  u16* lB = (u16*)(smem + 8192);
  const int tid = threadIdx.x;
  const int wave = tid >> 6;
  const int lane = tid & 63;
  const int wm = wave >> 1, wn = wave & 1;
  const int quad = lane >> 4, l16 = lane & 15;
  const int m0 = blockIdx.y * 128;
  const int n0 = blockIdx.x * 128;

  f32x4 acc[4][4] = {};

  const u16* gA = A + (size_t)(m0 + (tid >> 2)) * K_DIM + (tid & 3) * 8;
  const u16* gB = Bt + (size_t)(n0 + (tid >> 2)) * K_DIM + (tid & 3) * 8;
  u16* sA0 = lA + wave * 512;
  u16* sA1 = lA + 2048 + wave * 512;
  u16* sB0 = lB + wave * 512;
  u16* sB1 = lB + 2048 + wave * 512;

  const u16* rA = lA + (wm * 64 + l16) * 32 + quad * 8;
  const u16* rB = lB + (wn * 64 + l16) * 32 + quad * 8;

  for (int k0 = 0; k0 < K_DIM; k0 += 32) {
    __syncthreads();
    __builtin_amdgcn_global_load_lds((const __attribute__((address_space(1))) void*)(gA + k0),
                                     (__attribute__((address_space(3))) void*)sA0, 16, 0, 0);
    __builtin_amdgcn_global_load_lds((const __attribute__((address_space(1))) void*)(gA + (size_t)64 * K_DIM + k0),
                                     (__attribute__((address_space(3))) void*)sA1, 16, 0, 0);
    __builtin_amdgcn_global_load_lds((const __attribute__((address_space(1))) void*)(gB + k0),
                                     (__attribute__((address_space(3))) void*)sB0, 16, 0, 0);
    __builtin_amdgcn_global_load_lds((const __attribute__((address_space(1))) void*)(gB + (size_t)64 * K_DIM + k0),
                                     (__attribute__((address_space(3))) void*)sB1, 16, 0, 0);
    __syncthreads();

    bf16x8 af[4], bfr[4];
#pragma unroll
    for (int mt = 0; mt < 4; ++mt) af[mt] = *(const bf16x8*)(rA + mt * 16 * 32);
#pragma unroll
    for (int nt = 0; nt < 4; ++nt) bfr[nt] = *(const bf16x8*)(rB + nt * 16 * 32);
#pragma unroll
    for (int mt = 0; mt < 4; ++mt)
#pragma unroll
      for (int nt = 0; nt < 4; ++nt)
        acc[mt][nt] = __builtin_amdgcn_mfma_f32_16x16x32_bf16(af[mt], bfr[nt], acc[mt][nt], 0, 0, 0);
  }

  // ---- epilogue: acc -> LDS (bf16, stride 132) -> dwordx4 stores ----
  __syncthreads();
  u16* lC = (u16*)smem;
#pragma unroll
  for (int mt = 0; mt < 4; ++mt) {
#pragma unroll
    for (int nt = 0; nt < 4; ++nt) {
      int row = wm * 64 + mt * 16 + quad * 4;
      int col = wn * 64 + nt * 16 + l16;
#pragma unroll
      for (int r = 0; r < 4; ++r)
        lC[(row + r) * 132 + col] = f2bf(acc[mt][nt][r]);
    }
  }
  __syncthreads();
  int g = tid & 15;
  int r0w = tid >> 4;
#pragma unroll
  for (int it = 0; it < 8; ++it) {
    int row = r0w + it * 16;
    const u16* src = lC + row * 132 + g * 8;
    uint2 lo = *(const uint2*)src;
    uint2 hi = *(const uint2*)(src + 4);
    uint4 v = make_uint4(lo.x, lo.y, hi.x, hi.y);
    *(uint4*)(U + (size_t)(m0 + row) * N_DIM + n0 + g * 8) = v;
  }
}

// ---------------- SRU chunked affine scan, 8 chains per lane, CHUNK=16 ----------------
// 16B vector loads AND 8 waves/CU (round-3 lesson: these loops are latency-bound;
// 4 waves/CU starved the pipeline).

__global__ __launch_bounds__(256) void sru_phase1(const u16* __restrict__ U,
                                                  const float* __restrict__ bias,
                                                  float* __restrict__ Aarr,
                                                  float* __restrict__ Barr) {
  int tid = blockIdx.x * 256 + threadIdx.x;   // [NCHUNK][B][128]
  int j = tid >> 11;
  int b = (tid >> 7) & 15;
  int dg = tid & 127;
  int d0 = dg * 8;
  int chain0 = b * D_DIM + d0;
  float bb1[8];
#pragma unroll
  for (int i = 0; i < 8; ++i) bb1[i] = bias[d0 + i];
  const u16* p = U + (size_t)(j * CHUNK * B_DIM + b) * N_DIM + d0;
  float A[8], Bv[8];
#pragma unroll
  for (int i = 0; i < 8; ++i) { A[i] = 1.0f; Bv[i] = 0.0f; }
#pragma unroll 4
  for (int s = 0; s < CHUNK; ++s) {
    u16x8 u0v = *(const u16x8*)p;
    u16x8 g1v = *(const u16x8*)(p + D_DIM);
#pragma unroll
    for (int i = 0; i < 8; ++i) {
      float u0 = bf2f(u0v[i]);
      float g1 = sigm(bf2f(g1v[i]) + bb1[i]);
      Bv[i] = (Bv[i] - u0) * g1 + u0;
      A[i] *= g1;
    }
    p += (size_t)B_DIM * N_DIM;
  }
  float* Ap = Aarr + (size_t)j * CHAINS + chain0;
  float* Bp = Barr + (size_t)j * CHAINS + chain0;
  *(float4*)Ap = make_float4(A[0], A[1], A[2], A[3]);
  *(float4*)(Ap + 4) = make_float4(A[4], A[5], A[6], A[7]);
  *(float4*)Bp = make_float4(Bv[0], Bv[1], Bv[2], Bv[3]);
  *(float4*)(Bp + 4) = make_float4(Bv[4], Bv[5], Bv[6], Bv[7]);
}

__global__ __launch_bounds__(256) void sru_phase2(const float* __restrict__ Aarr,
                                                  const float* __restrict__ Barr,
                                                  const float* __restrict__ c0,
                                                  float* __restrict__ Cin,
                                                  float* __restrict__ clast) {
  int chain = blockIdx.x * 256 + threadIdx.x;
  float c = c0[chain];
#pragma unroll 8
  for (int j = 0; j < NCHUNK; ++j) {
    Cin[j * CHAINS + chain] = c;
    c = Aarr[j * CHAINS + chain] * c + Barr[j * CHAINS + chain];
  }
  clast[chain] = c;
}

__global__ __launch_bounds__(256) void sru_phase3(const u16* __restrict__ U,
                                                  const float* __restrict__ x,
                                                  const float* __restrict__ bias,
                                                  const float* __restrict__ Cin,
                                                  float* __restrict__ h) {
  int tid = blockIdx.x * 256 + threadIdx.x;
  int j = tid >> 11;
  int b = (tid >> 7) & 15;
  int dg = tid & 127;
  int d0 = dg * 8;
  int chain0 = b * D_DIM + d0;
  float bb1[8], bb2[8], c[8];
#pragma unroll
  for (int i = 0; i < 8; ++i) {
    bb1[i] = bias[d0 + i];
    bb2[i] = bias[D_DIM + d0 + i];
  }
  const float* cin = Cin + (size_t)j * CHAINS + chain0;
  float4 c_0 = *(const float4*)cin;
  float4 c_1 = *(const float4*)(cin + 4);
  c[0] = c_0.x; c[1] = c_0.y; c[2] = c_0.z; c[3] = c_0.w;
  c[4] = c_1.x; c[5] = c_1.y; c[6] = c_1.z; c[7] = c_1.w;
  size_t m0 = (size_t)(j * CHUNK * B_DIM + b);
  const u16* p = U + m0 * N_DIM + d0;
  const float* xp = x + m0 * D_DIM + d0;
  float* hp = h + m0 * D_DIM + d0;
#pragma unroll 2
  for (int s = 0; s < CHUNK; ++s) {
    u16x8 u0v = *(const u16x8*)p;
    u16x8 g1v = *(const u16x8*)(p + D_DIM);
    u16x8 g2v = *(const u16x8*)(p + 2 * D_DIM);
    float4 x0 = *(const float4*)xp;
    float4 x1 = *(const float4*)(xp + 4);
    float xs[8] = {x0.x, x0.y, x0.z, x0.w, x1.x, x1.y, x1.z, x1.w};
    float hs[8];
#pragma unroll
    for (int i = 0; i < 8; ++i) {
      float u0 = bf2f(u0v[i]);
      float g1 = sigm(bf2f(g1v[i]) + bb1[i]);
      float g2 = sigm(bf2f(g2v[i]) + bb2[i]);
      c[i] = (c[i] - u0) * g1 + u0;
      hs[i] = (ftanh(c[i]) - xs[i]) * g2 + xs[i];
    }
    *(float4*)hp = make_float4(hs[0], hs[1], hs[2], hs[3]);
    *(float4*)(hp + 4) = make_float4(hs[4], hs[5], hs[6], hs[7]);
    p += (size_t)B_DIM * N_DIM;
    xp += B_DIM * D_DIM;
    hp += B_DIM * D_DIM;
  }
}

extern "C" void kernel_launch(void* const* d_in, const int* in_sizes, int n_in,
                              void* d_out, int out_size, void* d_ws, size_t ws_size,
                              hipStream_t stream) {
  const float* x = (const float*)d_in[0];     // L*B*D
  const float* W = (const float*)d_in[1];     // K x 3D
  const float* bias = (const float*)d_in[2];  // 2D
  const float* c0 = (const float*)d_in[3];    // B*D
  float* out = (float*)d_out;

  char* ws = (char*)d_ws;
  u16* xb = (u16*)ws;                               // 32 MiB, dead after gemm
  u16* wt = (u16*)(ws + 33554432);                  // 6 MiB
  u16* U = (u16*)(ws + 33554432 + 6291456);         // 96 MiB
  // scan scratch overlaps dead xb region (gemm consumed xb before phase1 runs)
  float* Aarr = (float*)ws;                         // 4 MiB
  float* Barr = (float*)(ws + 4194304);             // 4 MiB
  float* Cin  = (float*)(ws + 8388608);             // 4 MiB

  cvt_x_kernel<<<16384, 256, 0, stream>>>((const float4*)x, (ushort4*)xb, M_DIM * K_DIM / 4);
  cvt_w_kernel<<<dim3(48, 16), 256, 0, stream>>>(W, wt);
  gemm_kernel<<<dim3(N_DIM / 128, M_DIM / 128), 256, 0, stream>>>(xb, wt, U);
  sru_phase1<<<CHAINS * NCHUNK / 8 / 256, 256, 0, stream>>>(U, bias, Aarr, Barr);
  sru_phase2<<<CHAINS / 256, 256, 0, stream>>>(Aarr, Barr, c0, Cin, out + (size_t)M_DIM * D_DIM);
  sru_phase3<<<CHAINS * NCHUNK / 8 / 256, 256, 0, stream>>>(U, x, bias, Cin, out);
}